// Round 1
// baseline (136.395 us; speedup 1.0000x reference)
//
#include <hip/hip_runtime.h>
#include <cstdint>
#include <cstddef>

#define DI __device__ __forceinline__

typedef __attribute__((ext_vector_type(8))) short short8;
typedef __attribute__((ext_vector_type(4))) float f32x4;

DI float bf2f(unsigned short u) {
  union { unsigned int i; float f; } c; c.i = ((unsigned int)u) << 16; return c.f;
}
DI unsigned short f2bf(float f) {
  union { float fl; unsigned int i; } c; c.fl = f;
  return (unsigned short)((c.i + 0x7FFFu + ((c.i >> 16) & 1u)) >> 16);
}

// ---- workspace layout (bytes) ----
static const size_t OFF_MASK = 256;                        // u8[2176] normalized mask
static const size_t OFF_XC   = 4096;                       // bf16 x       2048*512
static const size_t OFF_WST  = OFF_XC  + (size_t)2048*512*2;   // bf16 [qw;kvw] 1536*512
static const size_t OFF_AC   = OFF_WST + (size_t)1536*512*2;   // bf16 assignment padded 16384*24
static const size_t OFF_RB   = OFF_AC  + (size_t)16384*24*2;   // bf16 rel_bias 136 (pad 512B)
static const size_t OFF_PW   = OFF_RB  + 512;                  // bf16 proj_w 512*512
static const size_t OFF_PB   = OFF_PW  + (size_t)512*512*2;    // bf16 proj_b 512 (pad 1KB)
static const size_t OFF_XQKV = OFF_PB  + 1024;                 // bf16 2048*1536
static const size_t OFF_ATTO = OFF_XQKV+ (size_t)2048*1536*2;  // bf16 2048*512

// ---- dtype detection + mask normalization ----
// fmode: 0=bf16 inputs, 1=f32 inputs.  mmode: 0=u8, 1=i32, 2=bf16, 3=f32.
__global__ void k_detect(const unsigned char* __restrict__ xr,
                         const unsigned char* __restrict__ mr,
                         unsigned char* __restrict__ ws) {
  __shared__ int s_sane, s_3f, s_b1, s_odd;
  int t = threadIdx.x;
  if (t == 0) { s_sane = 0; s_3f = 0; s_b1 = 0; s_odd = 0; }
  __syncthreads();
  if (t < 128) {
    // even u16 indices: bf16 storage -> sane exponents; f32 storage -> random mantissa bits
    const unsigned short* xu = (const unsigned short*)xr;
    unsigned short u = xu[2 * t];
    int e = (u >> 7) & 0xFF;
    if (e >= 64 && e <= 150) atomicAdd(&s_sane, 1);
  }
  int f3 = 0, b1 = 0, od = 0;
  for (int i = t; i < 2176; i += 256) {   // first 2176 bytes are in-bounds for every candidate dtype
    unsigned char bb = mr[i];
    if (bb == 0x3F) f3 = 1;
    if (bb != 0) {
      if ((i & 3) == 1) b1 = 1;
      if ((i & 3) != 0) od = 1;
    }
  }
  if (f3) atomicOr(&s_3f, 1);
  if (b1) atomicOr(&s_b1, 1);
  if (od) atomicOr(&s_odd, 1);
  __syncthreads();
  int fmode = (s_sane >= 96) ? 0 : 1;
  int mmode = s_3f ? (s_b1 ? 2 : 3) : (s_odd ? 0 : 1);
  if (t == 0) { ((int*)ws)[0] = fmode; ((int*)ws)[1] = mmode; }
  unsigned char* mN = ws + OFF_MASK;
  for (int i = t; i < 2176; i += 256) {
    int v;
    if (mmode == 0)      v = mr[i] != 0;
    else if (mmode == 1) v = ((const int*)mr)[i] != 0;
    else if (mmode == 2) v = ((const unsigned short*)mr)[i] != 0;
    else                 v = ((const float*)mr)[i] != 0.0f;
    mN[i] = (unsigned char)v;
  }
}

// ---- convert all float tensors to canonical bf16 in ws ----
struct ConvArgs { const void *x, *as, *qw, *kvw, *rb, *pw, *pb; };

__global__ void k_convert(ConvArgs a, unsigned char* __restrict__ ws) {
  const int fmode = ((const int*)ws)[0];
  unsigned short* XC  = (unsigned short*)(ws + OFF_XC);
  unsigned short* WST = (unsigned short*)(ws + OFF_WST);
  unsigned short* AC  = (unsigned short*)(ws + OFF_AC);
  unsigned short* RB  = (unsigned short*)(ws + OFF_RB);
  unsigned short* PW  = (unsigned short*)(ws + OFF_PW);
  unsigned short* PB  = (unsigned short*)(ws + OFF_PB);
  for (int i = blockIdx.x * blockDim.x + threadIdx.x; i < 2376328;
       i += gridDim.x * blockDim.x) {
    const void* src; int local; unsigned short* dst; int didx;
    if (i < 1048576)      { src = a.x;   local = i;           dst = XC;  didx = local; }
    else if (i < 1327104) { src = a.as;  local = i - 1048576; dst = AC;  didx = (local / 17) * 24 + (local % 17); }
    else if (i < 1589248) { src = a.qw;  local = i - 1327104; dst = WST; didx = local; }
    else if (i < 2113536) { src = a.kvw; local = i - 1589248; dst = WST; didx = 262144 + local; }
    else if (i < 2113672) { src = a.rb;  local = i - 2113536; dst = RB;  didx = local; }
    else if (i < 2375816) { src = a.pw;  local = i - 2113672; dst = PW;  didx = local; }
    else                  { src = a.pb;  local = i - 2375816; dst = PB;  didx = local; }
    unsigned short v = fmode ? f2bf(((const float*)src)[local])
                             : ((const unsigned short*)src)[local];
    dst[didx] = v;
  }
}

// ---- generic bf16 GEMM: C[M,N] = A[M,K] @ B[N,K]^T (+bias), NT layout ----
__global__ __launch_bounds__(256) void k_gemm(const unsigned short* __restrict__ A,
                                              const unsigned short* __restrict__ B,
                                              unsigned short* __restrict__ C,
                                              const unsigned short* __restrict__ bias,
                                              const int* __restrict__ flagp,
                                              int M, int N, int K) {
  __shared__ unsigned short As[64][72];   // +8 pad: 2-way (free) bank pattern
  __shared__ unsigned short Bs[64][72];
  const int bm = blockIdx.x * 64, bn = blockIdx.y * 64;
  const int t = threadIdx.x;
  const int w = t >> 6, l = t & 63, ln = l & 15, qd = l >> 4;
  const int sr = t >> 2, sc = (t & 3) * 16;
  f32x4 acc[4] = {};
  const unsigned short* ap = A + (size_t)(bm + sr) * K + sc;
  const unsigned short* bp = B + (size_t)(bn + sr) * K + sc;
  for (int k0 = 0; k0 < K; k0 += 64) {
    *(uint4*)&As[sr][sc]     = *(const uint4*)(ap + k0);
    *(uint4*)&As[sr][sc + 8] = *(const uint4*)(ap + k0 + 8);
    *(uint4*)&Bs[sr][sc]     = *(const uint4*)(bp + k0);
    *(uint4*)&Bs[sr][sc + 8] = *(const uint4*)(bp + k0 + 8);
    __syncthreads();
#pragma unroll
    for (int kk = 0; kk < 64; kk += 32) {
      short8 af = *(const short8*)&As[w * 16 + ln][kk + qd * 8];
#pragma unroll
      for (int tj = 0; tj < 4; tj++) {
        short8 bf = *(const short8*)&Bs[tj * 16 + ln][kk + qd * 8];
        acc[tj] = __builtin_amdgcn_mfma_f32_16x16x32_bf16(af, bf, acc[tj], 0, 0, 0);
      }
    }
    __syncthreads();
  }
  const int of32 = flagp ? flagp[0] : 0;
#pragma unroll
  for (int tj = 0; tj < 4; tj++) {
    int col = bn + tj * 16 + ln;
    float bv = bias ? bf2f(bias[col]) : 0.0f;
#pragma unroll
    for (int i = 0; i < 4; i++) {
      int row = bm + w * 16 + qd * 4 + i;
      float v = acc[tj][i] + bv;
      if (of32) ((float*)C)[(size_t)row * N + col] = v;
      else      C[(size_t)row * N + col] = f2bf(v);
    }
  }
}

// ---- attention core: S = scale*q@k^T ; logits/softmax/W via assignment ; out = W@v ----
#define SSTRIDE 132   // f32 words per S row (pad 4)
#define WSTRIDE 264   // u16 per W row (same bytes as S row)
#define VSTRIDE 136   // u16 per vT row (pad 8)

__global__ __launch_bounds__(256) void k_attn(const unsigned short* __restrict__ XQKV,
                                              const unsigned short* __restrict__ AC,
                                              const unsigned char* __restrict__ maskN,
                                              const unsigned short* __restrict__ RB,
                                              unsigned short* __restrict__ ATTO) {
  __shared__ __align__(16) unsigned char sm0[64 * SSTRIDE * 4];  // S (f32), then W (bf16) in place
  __shared__ __align__(16) unsigned char sm1[64 * VSTRIDE * 2];  // v^T
  float* Sf = (float*)sm0;
  unsigned short* Wb = (unsigned short*)sm0;
  unsigned short* vT = (unsigned short*)sm1;

  const int blk = blockIdx.x;                 // (b*8 + h)*2 + mhalf
  const int mhalf = blk & 1, h = (blk >> 1) & 7, b = blk >> 4;
  const int t = threadIdx.x;
  const int w = t >> 6, l = t & 63, ln = l & 15, qd = l >> 4;

  // stage v^T: v[n][d] -> vT[d][n]
  {
    int n = t >> 1, d0 = (t & 1) * 32;
    const unsigned short* vp = XQKV + (size_t)(b * 128 + n) * 1536 + 1024 + h * 64 + d0;
#pragma unroll
    for (int c = 0; c < 4; c++) {
      uint4 u = *(const uint4*)(vp + c * 8);
      const unsigned short* us = (const unsigned short*)&u;
#pragma unroll
      for (int j = 0; j < 8; j++) vT[(d0 + c * 8 + j) * VSTRIDE + n] = us[j];
    }
  }

  // S rows [mhalf*64,+64) x cols [0,128): MFMA with operands straight from global (L2-hot)
  {
    f32x4 accS[8] = {};
    const int mrow = b * 128 + mhalf * 64 + w * 16 + ln;
#pragma unroll
    for (int kk = 0; kk < 64; kk += 32) {
      short8 af = *(const short8*)(XQKV + (size_t)mrow * 1536 + h * 64 + kk + qd * 8);
#pragma unroll
      for (int tj = 0; tj < 8; tj++) {
        const int nrow = b * 128 + tj * 16 + ln;
        short8 bf = *(const short8*)(XQKV + (size_t)nrow * 1536 + 512 + h * 64 + kk + qd * 8);
        accS[tj] = __builtin_amdgcn_mfma_f32_16x16x32_bf16(af, bf, accS[tj], 0, 0, 0);
      }
    }
#pragma unroll
    for (int tj = 0; tj < 8; tj++)
#pragma unroll
      for (int i = 0; i < 4; i++)
        Sf[(w * 16 + qd * 4 + i) * SSTRIDE + tj * 16 + ln] = accS[tj][i] * 0.125f;
  }
  __syncthreads();

  // per-row: logits over n (4 threads/row, shfl combine), mask+softmax, W row (bf16, overlays S)
  // safety: W writes only alias S bytes of the SAME row; all 4 row-threads are in one wave
  // (lockstep), so every S read of the row precedes every W write of the row.
  {
    const int ml = t >> 2, q4 = t & 3, n0 = q4 * 32;
    const int m = mhalf * 64 + ml;
    float lg[17];
#pragma unroll
    for (int r = 0; r < 17; r++) lg[r] = 0.0f;
    const unsigned short* arow = AC + ((size_t)m * 128 + n0) * 24;
    for (int nn = 0; nn < 32; nn++) {
      float sv = Sf[ml * SSTRIDE + n0 + nn];
      const unsigned short* apr = arow + nn * 24;
      uint4 va = *(const uint4*)apr;
      uint4 vb = *(const uint4*)(apr + 8);
      unsigned short vc = apr[16];
      const unsigned short* pa = (const unsigned short*)&va;
      const unsigned short* pb = (const unsigned short*)&vb;
#pragma unroll
      for (int j = 0; j < 8; j++) lg[j] += sv * bf2f(pa[j]);
#pragma unroll
      for (int j = 0; j < 8; j++) lg[8 + j] += sv * bf2f(pb[j]);
      lg[16] += sv * bf2f(vc);
    }
#pragma unroll
    for (int r = 0; r < 17; r++) {
      float v = lg[r];
      v += __shfl_xor(v, 1);
      v += __shfl_xor(v, 2);
      lg[r] = v;
    }
    int mb = 0;
    float mx = -3.0e38f;
#pragma unroll
    for (int r = 0; r < 17; r++) {
      if (maskN[m * 17 + r]) mb |= (1 << r);
      lg[r] += bf2f(RB[h * 17 + r]);
    }
#pragma unroll
    for (int r = 0; r < 17; r++)
      if (!((mb >> r) & 1) && lg[r] > mx) mx = lg[r];
    float sum = 0.0f;
#pragma unroll
    for (int r = 0; r < 17; r++) {
      float e = ((mb >> r) & 1) ? 0.0f : __expf(lg[r] - mx);
      lg[r] = e;
      sum += e;
    }
    float inv = 1.0f / sum;
    for (int nn = 0; nn < 32; nn++) {
      const unsigned short* apr = arow + nn * 24;
      uint4 va = *(const uint4*)apr;
      uint4 vb = *(const uint4*)(apr + 8);
      unsigned short vc = apr[16];
      const unsigned short* pa = (const unsigned short*)&va;
      const unsigned short* pb = (const unsigned short*)&vb;
      float acc = 0.0f;
#pragma unroll
      for (int j = 0; j < 8; j++) acc += lg[j] * bf2f(pa[j]);
#pragma unroll
      for (int j = 0; j < 8; j++) acc += lg[8 + j] * bf2f(pb[j]);
      acc += lg[16] * bf2f(vc);
      Wb[ml * WSTRIDE + n0 + nn] = f2bf(acc * inv);
    }
  }
  __syncthreads();

  // out = W(64x128) @ v(128x64) via vT
  {
    f32x4 accO[4] = {};
#pragma unroll
    for (int kk = 0; kk < 128; kk += 32) {
      short8 af = *(const short8*)&Wb[(w * 16 + ln) * WSTRIDE + kk + qd * 8];
#pragma unroll
      for (int tj = 0; tj < 4; tj++) {
        short8 bf = *(const short8*)&vT[(tj * 16 + ln) * VSTRIDE + kk + qd * 8];
        accO[tj] = __builtin_amdgcn_mfma_f32_16x16x32_bf16(af, bf, accO[tj], 0, 0, 0);
      }
    }
#pragma unroll
    for (int tj = 0; tj < 4; tj++) {
      int d = tj * 16 + ln;
#pragma unroll
      for (int i = 0; i < 4; i++) {
        int mloc = w * 16 + qd * 4 + i;
        ATTO[(size_t)(b * 128 + mhalf * 64 + mloc) * 512 + h * 64 + d] = f2bf(accO[tj][i]);
      }
    }
  }
}

extern "C" void kernel_launch(void* const* d_in, const int* in_sizes, int n_in,
                              void* d_out, int out_size, void* d_ws, size_t ws_size,
                              hipStream_t stream) {
  unsigned char* ws = (unsigned char*)d_ws;
  // 0:x 1:assignment 2:mask 3:q_w 4:kv_w 5:rel_bias 6:proj_w 7:proj_b
  k_detect<<<1, 256, 0, stream>>>((const unsigned char*)d_in[0],
                                  (const unsigned char*)d_in[2], ws);
  ConvArgs ca{d_in[0], d_in[1], d_in[3], d_in[4], d_in[5], d_in[6], d_in[7]};
  k_convert<<<1024, 256, 0, stream>>>(ca, ws);
  // xqkv = x @ [q_w; kv_w]^T   (2048x512 @ 512x1536)
  k_gemm<<<dim3(32, 24), 256, 0, stream>>>((const unsigned short*)(ws + OFF_XC),
                                           (const unsigned short*)(ws + OFF_WST),
                                           (unsigned short*)(ws + OFF_XQKV),
                                           nullptr, nullptr, 2048, 1536, 512);
  // attention core: 256 blocks = (b,h,row-half)
  k_attn<<<256, 256, 0, stream>>>((const unsigned short*)(ws + OFF_XQKV),
                                  (const unsigned short*)(ws + OFF_AC),
                                  ws + OFF_MASK,
                                  (const unsigned short*)(ws + OFF_RB),
                                  (unsigned short*)(ws + OFF_ATTO));
  // final projection + bias (output dtype follows detected input dtype)
  k_gemm<<<dim3(32, 8), 256, 0, stream>>>((const unsigned short*)(ws + OFF_ATTO),
                                          (const unsigned short*)(ws + OFF_PW),
                                          (unsigned short*)d_out,
                                          (const unsigned short*)(ws + OFF_PB),
                                          (const int*)d_ws, 2048, 512, 512);
}